// Round 3
// baseline (433.962 us; speedup 1.0000x reference)
//
#include <hip/hip_runtime.h>
#include <math.h>

#define NRAYS 8192
#define NSAMP 256
#define GD    160
#define NVOX  (GD*GD*GD)
#define CF    12
#define HID   128
#define W0P8  56            // s_w0a row pitch BYTES (48 data + 8 pad)
#define W1P8  136           // s_w1a row pitch BYTES (128 data + 8 pad)
#define TAU   2e-6f         // weight cull threshold: err <= 0.5*256*TAU = 2.6e-4 << 2e-2
#define NSEG  64            // reservation-counter segments (kills same-address atomic serialization)
#define CSTR  64            // counter stride in u32 (256 B apart -> distinct lines/channels)

// ws layout: [cnt u32 x64, 256B apart -> 16 KB] [bf16 z-pair table 4B*NVOX = 16.4 MB] [segmented entry lists]
// z-pair table: 4x smaller than the old 16B/cell corner table -> in-dispatch L2/L3 reuse
// (the harness's 768MB ws re-poison evicts caches between iterations, so footprint matters).
#define WS_ZP_OFF   ((size_t)16384)
#define WS_LIST_OFF (WS_ZP_OFF + (size_t)NVOX * 4)

static constexpr float ACT_SHIFT = -13.815509557963774f;
static constexpr float EPSF      = 1e-10f;

typedef __attribute__((ext_vector_type(16))) float f32x16;

__device__ __forceinline__ unsigned short bf16rne(float f) {
    unsigned u = __float_as_uint(f);
    return (unsigned short)((u + 0x7FFFu + ((u >> 16) & 1u)) >> 16);
}
__device__ __forceinline__ float bf16lo(unsigned u) { return __uint_as_float(u << 16); }
__device__ __forceinline__ float bf16hi(unsigned u) { return __uint_as_float(u & 0xffff0000u); }
__device__ __forceinline__ unsigned pk4(float a, float b, float c, float d) {
    int u = __builtin_amdgcn_cvt_pk_fp8_f32(a, b, 0, false);
    u     = __builtin_amdgcn_cvt_pk_fp8_f32(c, d, u, true);
    return (unsigned)u;
}
__device__ __forceinline__ unsigned char fp8b(float x) {
    return (unsigned char)(__builtin_amdgcn_cvt_pk_fp8_f32(x, x, 0, false) & 0xff);
}
__device__ __forceinline__ long long mk64(unsigned lo, unsigned hi) {
    return (long long)(((unsigned long long)hi << 32) | (unsigned long long)lo);
}

__device__ __forceinline__ void addr_calc(float px, float py, float pz,
                                          float& fx, float& fy, float& fz, int& base) {
    px = fminf(fmaxf(px, 0.f), 1.f) * (float)(GD - 1);
    py = fminf(fmaxf(py, 0.f), 1.f) * (float)(GD - 1);
    pz = fminf(fmaxf(pz, 0.f), 1.f) * (float)(GD - 1);
    int ix = min((int)px, GD - 2);
    int iy = min((int)py, GD - 2);
    int iz = min((int)pz, GD - 2);
    fx = px - (float)ix; fy = py - (float)iy; fz = pz - (float)iz;
    base = (ix * GD + iy) * GD + iz;
}

// ---------- K1: density -> bf16 z-pair table (4 B/voxel: bf16 d[z] | bf16 d[z+1] << 16) ----------
__global__ __launch_bounds__(256)
void prep_zp(const float* __restrict__ dg, unsigned* __restrict__ zp)
{
    int iz = threadIdx.x;            // 0..159
    int iy = blockIdx.x;
    int ix = blockIdx.y;
    int row = (ix * GD + iy) * GD;
    int zpp = min(iz + 1, GD - 1);
    unsigned lo = (unsigned)bf16rne(dg[row + iz]);
    unsigned hi = (unsigned)bf16rne(dg[row + zpp]);
    zp[row + iz] = lo | (hi << 16);
}

// ---------- K2: dense pass — alpha/scan/ainv + weight-cull compaction ----------
// Density via 4 independent 4-B gathers into the 16.4 MB z-pair table (L2/L3-resident
// within the dispatch; ~32x line reuse). Compaction counter segmented 64-way.
__global__ __launch_bounds__(256)
void pass_a(const float* __restrict__ ray_pts, const unsigned* __restrict__ zp,
            float* __restrict__ out, uint2* __restrict__ list,
            unsigned* __restrict__ cnt, unsigned segcap)
{
    __shared__ float s_wtot[4];
    __shared__ float s_skip[4];
    const int ray = blockIdx.x, t = threadIdx.x;
    const int lane = t & 63, w = t >> 6;
    const unsigned seg = (unsigned)blockIdx.x & (NSEG - 1u);

    float px = ray_pts[(ray * NSAMP + t) * 3 + 0];
    float py = ray_pts[(ray * NSAMP + t) * 3 + 1];
    float pz = ray_pts[(ray * NSAMP + t) * 3 + 2];
    float fx, fy, fz; int base;
    addr_calc(px, py, pz, fx, fy, fz, base);
    float wx0 = 1.f - fx, wy0 = 1.f - fy, wz0 = 1.f - fz;

    // four xy-corner columns; each dword holds (d[iz], d[iz+1]) bf16-packed
    unsigned r00 = zp[base];
    unsigned r01 = zp[base + GD];
    unsigned r10 = zp[base + GD * GD];
    unsigned r11 = zp[base + GD * GD + GD];
    float w00 = wx0 * wy0, w01 = wx0 * fy, w10 = fx * wy0, w11 = fx * fy;
    float dens =
        (bf16lo(r00) * wz0 + bf16hi(r00) * fz) * w00 +
        (bf16lo(r01) * wz0 + bf16hi(r01) * fz) * w01 +
        (bf16lo(r10) * wz0 + bf16hi(r10) * fz) * w10 +
        (bf16lo(r11) * wz0 + bf16hi(r11) * fz) * w11;

    float sv    = dens + ACT_SHIFT;
    float rs    = rsqrtf(1.0f + __expf(sv));
    float alpha = 1.0f - rs;
    float x     = rs + EPSF;                // 1 - alpha + EPS
    #pragma unroll
    for (int off = 1; off < 64; off <<= 1) {
        float y = __shfl_up(x, off);
        if (lane >= off) x *= y;
    }
    if (lane == 63) s_wtot[w] = x;
    __syncthreads();
    float t0 = s_wtot[0], t1 = s_wtot[1], t2 = s_wtot[2], t3 = s_wtot[3];
    float pre = 1.f;
    if (w > 0) pre *= t0;
    if (w > 1) pre *= t1;
    if (w > 2) pre *= t2;
    const float ainv = t0 * t1 * t2 * t3;
    float ex = __shfl_up(x, 1);
    if (lane == 0) ex = 1.f;
    const float wgt = alpha * ex * pre;

    // ---- cull + wave compaction (per-segment counter) ----
    bool keep = wgt > TAU;
    unsigned long long mask = __ballot(keep);
    int n = __popcll(mask);
    unsigned bslot = 0;
    if (lane == 0 && n) bslot = atomicAdd(cnt + seg * CSTR, (unsigned)n);
    bslot = (unsigned)__shfl((int)bslot, 0);
    int off2 = __popcll(mask & ((1ull << lane) - 1ull));
    unsigned slot = bslot + (unsigned)off2;
    bool kept = keep && (slot < segcap);
    if (kept) list[(size_t)seg * segcap + slot] =
        make_uint2((unsigned)(ray * NSAMP + t), __float_as_uint(wgt));

    // skipped samples contribute 0.5*wgt (rgb ~ 0.5); bound 0.5*256*TAU
    float skipw = kept ? 0.f : wgt;
    #pragma unroll
    for (int o = 32; o > 0; o >>= 1) skipw += __shfl_down(skipw, o);
    if (lane == 0) s_skip[w] = skipw;
    __syncthreads();
    if (t == 0) {
        float o = ainv + 0.5f * (s_skip[0] + s_skip[1] + s_skip[2] + s_skip[3]);
        out[ray * 3 + 0] = o; out[ray * 3 + 1] = o; out[ray * 3 + 2] = o;
    }
}

// ---------- K3: sparse pass — fp8 MFMA MLP over the 64 compacted sub-lists ----------
__global__ __launch_bounds__(256)
void pass_b(const float* __restrict__ ray_pts, const float* __restrict__ viewdirs,
            const float* __restrict__ k0,
            const float* __restrict__ w0, const float* __restrict__ b0,
            const float* __restrict__ w1, const float* __restrict__ b1,
            const float* __restrict__ w2, const float* __restrict__ b2,
            const uint2* __restrict__ list, const unsigned* __restrict__ cntp,
            unsigned segcap, float* __restrict__ out)
{
    __shared__ __align__(16) unsigned char s_w1a[HID * W1P8];
    __shared__ __align__(16) unsigned char s_w0a[HID * W0P8];
    __shared__ __align__(16) float4 s_w2b[HID];
    __shared__ unsigned s_pre[NSEG + 1];    // exclusive prefix of per-segment counts
    const int t = threadIdx.x, lane = t & 63, wv = t >> 6;
    const int nidx = lane & 31, qh = lane >> 5;

    for (int e = t; e < HID * HID; e += 256) {
        int i = e >> 7, o = e & 127;
        s_w1a[o * W1P8 + i] = fp8b(w1[e]);
    }
    for (int e = t; e < 39 * HID; e += 256) {
        int i = e >> 7, o = e & 127;
        s_w0a[o * W0P8 + i] = fp8b(w0[e]);
    }
    if (t < HID) {
        s_w0a[t * W0P8 + 39] = fp8b(b0[t]);   // bias via ones-entry (k=39)
        #pragma unroll
        for (int i = 40; i < 48; ++i) s_w0a[t * W0P8 + i] = 0;
        s_w2b[t] = make_float4(w2[t * 3 + 0], w2[t * 3 + 1], w2[t * 3 + 2], b1[t]);
    }
    if (t == 0) {
        unsigned acc = 0;
        s_pre[0] = 0;
        #pragma unroll 4
        for (int s = 0; s < NSEG; ++s) {
            unsigned n = cntp[s * CSTR];
            if (n > segcap) n = segcap;
            acc += n;
            s_pre[s + 1] = acc;
        }
    }
    const float b2x = b2[0], b2y = b2[1], b2z = b2[2];
    __syncthreads();

    const unsigned total = s_pre[NSEG];
    const unsigned stride = gridDim.x * 4 * 64;

    for (unsigned ib = (blockIdx.x * 4 + wv) * 64; ib < total; ib += stride) {
        unsigned i = ib + (unsigned)lane;
        uint2 e = make_uint2(0u, 0u);
        if (i < total) {
            // map flat index -> (segment, local) via 6-step binary search in LDS
            int lo = 0, hi = NSEG;
            #pragma unroll
            for (int st = 0; st < 6; ++st) {
                int mid = (lo + hi) >> 1;
                if (i >= s_pre[mid]) lo = mid; else hi = mid;
            }
            e = list[(size_t)lo * segcap + (i - s_pre[lo])];
        }
        float wgt = __uint_as_float(e.y);       // 0 for tail lanes
        unsigned sid = e.x;
        unsigned ray = sid >> 8;

        // ---- raw fp32 feat gather (tiny count) ----
        float px = ray_pts[sid * 3 + 0];
        float py = ray_pts[sid * 3 + 1];
        float pz = ray_pts[sid * 3 + 2];
        float fx, fy, fz; int base;
        addr_calc(px, py, pz, fx, fy, fz, base);
        float wxa[2] = {1.f - fx, fx}, wya[2] = {1.f - fy, fy}, wza[2] = {1.f - fz, fz};
        float feat[CF];
        #pragma unroll
        for (int c = 0; c < CF; ++c) feat[c] = 0.f;
        #pragma unroll
        for (int dx = 0; dx < 2; ++dx)
        #pragma unroll
        for (int dy = 0; dy < 2; ++dy)
        #pragma unroll
        for (int dz = 0; dz < 2; ++dz) {
            int idx = base + dx * (GD * GD) + dy * GD + dz;
            float wc = wxa[dx] * wya[dy] * wza[dz];
            const float4* kp = (const float4*)(k0 + (long)idx * CF);
            float4 a = kp[0], b = kp[1], c = kp[2];
            feat[0]  = fmaf(a.x, wc, feat[0]);  feat[1]  = fmaf(a.y, wc, feat[1]);
            feat[2]  = fmaf(a.z, wc, feat[2]);  feat[3]  = fmaf(a.w, wc, feat[3]);
            feat[4]  = fmaf(b.x, wc, feat[4]);  feat[5]  = fmaf(b.y, wc, feat[5]);
            feat[6]  = fmaf(b.z, wc, feat[6]);  feat[7]  = fmaf(b.w, wc, feat[7]);
            feat[8]  = fmaf(c.x, wc, feat[8]);  feat[9]  = fmaf(c.y, wc, feat[9]);
            feat[10] = fmaf(c.z, wc, feat[10]); feat[11] = fmaf(c.w, wc, feat[11]);
        }

        // ---- per-sample view embedding ----
        float vx = viewdirs[ray * 3 + 0], vy = viewdirs[ray * 3 + 1], vz = viewdirs[ray * 3 + 2];
        float inv = 1.0f / (sqrtf(vx * vx + vy * vy + vz * vz) + EPSF);
        float ve[27];
        ve[0] = vx * inv; ve[1] = vy * inv; ve[2] = vz * inv;
        #pragma unroll
        for (int ii = 0; ii < 3; ++ii)
            #pragma unroll
            for (int f = 0; f < 4; ++f) {
                float ang = ve[ii] * (float)(1 << f);
                ve[3  + ii * 4 + f] = __sinf(ang);
                ve[15 + ii * 4 + f] = __cosf(ang);
            }
        // k-stream fp8 dwords d0..d11 (k0..47): feats, vemb, 1.0 at k39, zeros
        unsigned d[12];
        d[0] = pk4(feat[0], feat[1], feat[2],  feat[3]);
        d[1] = pk4(feat[4], feat[5], feat[6],  feat[7]);
        d[2] = pk4(feat[8], feat[9], feat[10], feat[11]);
        #pragma unroll
        for (int q = 0; q < 6; ++q)
            d[3 + q] = pk4(ve[4*q], ve[4*q+1], ve[4*q+2], ve[4*q+3]);
        d[9] = pk4(ve[24], ve[25], ve[26], 1.0f);
        d[10] = 0u; d[11] = 0u;

        // ---- layer0 B-frags via shuffles (per-sample everything) ----
        long long bk[2][3];
        #pragma unroll
        for (int nt = 0; nt < 2; ++nt) {
            int src = nt * 32 + nidx;
            #pragma unroll
            for (int kt = 0; kt < 3; ++kt) {
                unsigned a0 = __shfl(d[4*kt+0], src), a1 = __shfl(d[4*kt+1], src);
                unsigned a2 = __shfl(d[4*kt+2], src), a3 = __shfl(d[4*kt+3], src);
                bk[nt][kt] = qh ? mk64(a2, a3) : mk64(a0, a1);
            }
        }

        // ---- layer0 MFMA + relu + fp8 repack ----
        unsigned p4A[4][4], p4B[4][4];
        #pragma unroll
        for (int mt = 0; mt < 4; ++mt) {
            f32x16 aA = {}, aB = {};
            const unsigned char* w0row = &s_w0a[(nidx + mt * 32) * W0P8 + qh * 8];
            #pragma unroll
            for (int kk = 0; kk < 3; ++kk) {
                long long af = *(const long long*)(w0row + kk * 16);
                aA = __builtin_amdgcn_mfma_f32_32x32x16_fp8_fp8(af, bk[0][kk], aA, 0, 0, 0);
                aB = __builtin_amdgcn_mfma_f32_32x32x16_fp8_fp8(af, bk[1][kk], aB, 0, 0, 0);
            }
            #pragma unroll
            for (int q = 0; q < 4; ++q) {
                p4A[mt][q] = pk4(fmaxf(aA[4*q+0], 0.f), fmaxf(aA[4*q+1], 0.f),
                                 fmaxf(aA[4*q+2], 0.f), fmaxf(aA[4*q+3], 0.f));
                p4B[mt][q] = pk4(fmaxf(aB[4*q+0], 0.f), fmaxf(aB[4*q+1], 0.f),
                                 fmaxf(aB[4*q+2], 0.f), fmaxf(aB[4*q+3], 0.f));
            }
        }

        // ---- C->B transition ----
        long long hfA[8], hfB[8];
        #pragma unroll
        for (int kt = 0; kt < 8; ++kt) {
            const int mt = kt >> 1, b = kt & 1;
            unsigned srcA = qh ? p4A[mt][2*b+1] : p4A[mt][2*b];
            unsigned srcB = qh ? p4B[mt][2*b+1] : p4B[mt][2*b];
            hfA[kt] = mk64(__shfl(srcA, nidx), __shfl(srcA, nidx + 32));
            hfB[kt] = mk64(__shfl(srcB, nidx), __shfl(srcB, nidx + 32));
        }

        // ---- layer1 MFMA + layer2 ----
        float rA0 = 0.f, rA1 = 0.f, rA2 = 0.f;
        float rB0 = 0.f, rB1 = 0.f, rB2 = 0.f;
        #pragma unroll
        for (int mt2 = 0; mt2 < 4; ++mt2) {
            f32x16 cA = {}, cB = {};
            const unsigned char* w1row = &s_w1a[(nidx + mt2 * 32) * W1P8 + qh * 8];
            #pragma unroll
            for (int kt = 0; kt < 8; ++kt) {
                long long af = *(const long long*)(w1row + kt * 16);
                cA = __builtin_amdgcn_mfma_f32_32x32x16_fp8_fp8(af, hfA[kt], cA, 0, 0, 0);
                cB = __builtin_amdgcn_mfma_f32_32x32x16_fp8_fp8(af, hfB[kt], cB, 0, 0, 0);
            }
            #pragma unroll
            for (int reg = 0; reg < 16; ++reg) {
                int dim = mt2 * 32 + (reg & 3) + 8 * (reg >> 2) + 4 * qh;
                float4 wb = s_w2b[dim];
                float hvA = fmaxf(cA[reg] + wb.w, 0.f);
                rA0 = fmaf(hvA, wb.x, rA0); rA1 = fmaf(hvA, wb.y, rA1); rA2 = fmaf(hvA, wb.z, rA2);
                float hvB = fmaxf(cB[reg] + wb.w, 0.f);
                rB0 = fmaf(hvB, wb.x, rB0); rB1 = fmaf(hvB, wb.y, rB1); rB2 = fmaf(hvB, wb.z, rB2);
            }
        }
        rA0 += __shfl_xor(rA0, 32); rA1 += __shfl_xor(rA1, 32); rA2 += __shfl_xor(rA2, 32);
        rB0 += __shfl_xor(rB0, 32); rB1 += __shfl_xor(rB1, 32); rB2 += __shfl_xor(rB2, 32);

        // per-sample scatter: qh==0 lanes own tile-A sample nidx, qh==1 own tile-B
        float wgtS; unsigned sidS; float r0, r1, r2;
        if (qh == 0) {
            wgtS = __shfl(wgt, nidx);          sidS = (unsigned)__shfl((int)sid, nidx);
            r0 = rA0; r1 = rA1; r2 = rA2;
        } else {
            wgtS = __shfl(wgt, nidx + 32);     sidS = (unsigned)__shfl((int)sid, nidx + 32);
            r0 = rB0; r1 = rB1; r2 = rB2;
        }
        if (wgtS != 0.f) {
            unsigned rs_ = sidS >> 8;
            float c0 = wgtS * __builtin_amdgcn_rcpf(1.f + __expf(-(r0 + b2x)));
            float c1 = wgtS * __builtin_amdgcn_rcpf(1.f + __expf(-(r1 + b2y)));
            float c2 = wgtS * __builtin_amdgcn_rcpf(1.f + __expf(-(r2 + b2z)));
            atomicAdd(&out[rs_ * 3 + 0], c0);
            atomicAdd(&out[rs_ * 3 + 1], c1);
            atomicAdd(&out[rs_ * 3 + 2], c2);
        }
    }
}

// ---------- emergency fallback (ws too small): density-only, rgb ~ 0.5 ----------
__global__ __launch_bounds__(256)
void dvgo_fallback(const float* __restrict__ ray_pts, const float* __restrict__ dg,
                   float* __restrict__ out)
{
    __shared__ float s_wtot[4];
    __shared__ float s_sum[4];
    const int ray = blockIdx.x, t = threadIdx.x;
    const int lane = t & 63, w = t >> 6;
    float px = ray_pts[(ray * NSAMP + t) * 3 + 0];
    float py = ray_pts[(ray * NSAMP + t) * 3 + 1];
    float pz = ray_pts[(ray * NSAMP + t) * 3 + 2];
    float fx, fy, fz; int base;
    addr_calc(px, py, pz, fx, fy, fz, base);
    float wxa[2] = {1.f - fx, fx}, wya[2] = {1.f - fy, fy}, wza[2] = {1.f - fz, fz};
    float dens = 0.f;
    #pragma unroll
    for (int dx = 0; dx < 2; ++dx)
    #pragma unroll
    for (int dy = 0; dy < 2; ++dy)
    #pragma unroll
    for (int dz = 0; dz < 2; ++dz)
        dens = fmaf(dg[base + dx*(GD*GD) + dy*GD + dz], wxa[dx]*wya[dy]*wza[dz], dens);
    float rs = rsqrtf(1.0f + __expf(dens + ACT_SHIFT));
    float alpha = 1.0f - rs;
    float x = rs + EPSF;
    #pragma unroll
    for (int off = 1; off < 64; off <<= 1) {
        float y = __shfl_up(x, off);
        if (lane >= off) x *= y;
    }
    if (lane == 63) s_wtot[w] = x;
    __syncthreads();
    float t0 = s_wtot[0], t1 = s_wtot[1], t2 = s_wtot[2], t3 = s_wtot[3];
    float pre = 1.f;
    if (w > 0) pre *= t0;
    if (w > 1) pre *= t1;
    if (w > 2) pre *= t2;
    float ainv = t0 * t1 * t2 * t3;
    float ex = __shfl_up(x, 1);
    if (lane == 0) ex = 1.f;
    float wgt = alpha * ex * pre;
    #pragma unroll
    for (int o = 32; o > 0; o >>= 1) wgt += __shfl_down(wgt, o);
    if (lane == 0) s_sum[w] = wgt;
    __syncthreads();
    if (t == 0) {
        float o = ainv + 0.5f * (s_sum[0] + s_sum[1] + s_sum[2] + s_sum[3]);
        out[ray * 3 + 0] = o; out[ray * 3 + 1] = o; out[ray * 3 + 2] = o;
    }
}

extern "C" void kernel_launch(void* const* d_in, const int* in_sizes, int n_in,
                              void* d_out, int out_size, void* d_ws, size_t ws_size,
                              hipStream_t stream) {
    const float* ray_pts      = (const float*)d_in[0];
    const float* viewdirs     = (const float*)d_in[1];
    const float* density_grid = (const float*)d_in[2];
    const float* k0           = (const float*)d_in[3];
    const float* w0           = (const float*)d_in[4];
    const float* b0           = (const float*)d_in[5];
    const float* w1           = (const float*)d_in[6];
    const float* b1           = (const float*)d_in[7];
    const float* w2           = (const float*)d_in[8];
    const float* b2           = (const float*)d_in[9];
    float*       outp         = (float*)d_out;

    const size_t min_ws = WS_LIST_OFF + (size_t)65536 * 8;   // z-pair table + minimal list
    if (ws_size >= min_ws) {
        unsigned* cnt  = (unsigned*)d_ws;
        unsigned* zp   = (unsigned*)((char*)d_ws + WS_ZP_OFF);
        uint2*    list = (uint2*)((char*)d_ws + WS_LIST_OFF);
        size_t cap_sz = (ws_size - WS_LIST_OFF) / 8;
        size_t sc = cap_sz / NSEG;
        unsigned segcap = (unsigned)((sc > (size_t)32768) ? (size_t)32768 : sc);  // 128 rays/seg * 256 max

        hipMemsetAsync(cnt, 0, NSEG * CSTR * sizeof(unsigned), stream);
        prep_zp<<<dim3(GD, GD), dim3(GD), 0, stream>>>(density_grid, zp);
        pass_a<<<dim3(NRAYS), dim3(NSAMP), 0, stream>>>(ray_pts, zp, outp, list, cnt, segcap);
        pass_b<<<dim3(256), dim3(256), 0, stream>>>(ray_pts, viewdirs, k0,
                                                    w0, b0, w1, b1, w2, b2,
                                                    list, cnt, segcap, outp);
    } else {
        dvgo_fallback<<<dim3(NRAYS), dim3(NSAMP), 0, stream>>>(ray_pts, density_grid, outp);
    }
}

// Round 4
// 360.975 us; speedup vs baseline: 1.2022x; 1.2022x over previous
//
#include <hip/hip_runtime.h>
#include <math.h>

#define NRAYS 8192
#define NSAMP 256
#define GD    160
#define NVOX  (GD*GD*GD)
#define CF    12
#define HID   128
#define W0P8  56            // s_w0a row pitch BYTES (48 data + 8 pad)
#define W1P8  136           // s_w1a row pitch BYTES (128 data + 8 pad)
#define TAU   2e-6f         // weight cull threshold: err <= 0.5*256*TAU = 2.6e-4 << 2e-2
#define NSEG  64            // reservation-counter segments (kills same-address atomic serialization)
#define CSTR  64            // counter stride in u32 (256 B apart -> distinct lines/channels)

// ws layout: [cnt u32 x64, 256B apart -> 16 KB] [fp8 corner records 8B*NVOX = 32.8 MB] [segmented entry lists]
// ONE 8-B gather per sample (transaction-bound, not byte-bound: R3 showed 4x4B gathers
// quadruple TA transactions and cost +69us; 1x16B bf16 was 365us total; fp8 halves bytes
// at identical transaction count).
#define WS_REC_OFF  ((size_t)16384)
#define WS_LIST_OFF (WS_REC_OFF + (size_t)NVOX * 8)

static constexpr float ACT_SHIFT = -13.815509557963774f;
static constexpr float EPSF      = 1e-10f;

typedef __attribute__((ext_vector_type(16))) float f32x16;

__device__ __forceinline__ unsigned pk4(float a, float b, float c, float d) {
    int u = __builtin_amdgcn_cvt_pk_fp8_f32(a, b, 0, false);
    u     = __builtin_amdgcn_cvt_pk_fp8_f32(c, d, u, true);
    return (unsigned)u;
}
__device__ __forceinline__ unsigned char fp8b(float x) {
    return (unsigned char)(__builtin_amdgcn_cvt_pk_fp8_f32(x, x, 0, false) & 0xff);
}
__device__ __forceinline__ long long mk64(unsigned lo, unsigned hi) {
    return (long long)(((unsigned long long)hi << 32) | (unsigned long long)lo);
}

__device__ __forceinline__ void addr_calc(float px, float py, float pz,
                                          float& fx, float& fy, float& fz, int& base) {
    px = fminf(fmaxf(px, 0.f), 1.f) * (float)(GD - 1);
    py = fminf(fmaxf(py, 0.f), 1.f) * (float)(GD - 1);
    pz = fminf(fmaxf(pz, 0.f), 1.f) * (float)(GD - 1);
    int ix = min((int)px, GD - 2);
    int iy = min((int)py, GD - 2);
    int iz = min((int)pz, GD - 2);
    fx = px - (float)ix; fy = py - (float)iy; fz = pz - (float)iz;
    base = (ix * GD + iy) * GD + iz;
}

// ---------- K1: density -> replicated 2x2x2 fp8 corner records (8 B/cell) ----------
// byte c = corner (dx*4 + dy*2 + dz). Also zeroes the 64 segment counters (block 0).
__global__ __launch_bounds__(256)
void prep_rec8(const float* __restrict__ dg, unsigned long long* __restrict__ rec,
               unsigned* __restrict__ cnt)
{
    int iz = threadIdx.x;            // 0..159
    int iy = blockIdx.x;
    int ix = blockIdx.y;
    if (iy == 0 && ix == 0 && iz < NSEG) cnt[iz * CSTR] = 0;   // merged memset
    int xp = min(ix + 1, GD - 1), yp = min(iy + 1, GD - 1), zp = min(iz + 1, GD - 1);
    int r00 = (ix * GD + iy) * GD, r01 = (ix * GD + yp) * GD;
    int r10 = (xp * GD + iy) * GD, r11 = (xp * GD + yp) * GD;
    unsigned lo = pk4(dg[r00 + iz], dg[r00 + zp], dg[r01 + iz], dg[r01 + zp]);
    unsigned hi = pk4(dg[r10 + iz], dg[r10 + zp], dg[r11 + iz], dg[r11 + zp]);
    rec[(ix * GD + iy) * GD + iz] = ((unsigned long long)hi << 32) | (unsigned long long)lo;
}

// ---------- K2: dense pass — alpha/scan/ainv + weight-cull compaction ----------
// Density via ONE 8-B gather (fp8 x8 corners). Compaction counter segmented 64-way.
__global__ __launch_bounds__(256)
void pass_a(const float* __restrict__ ray_pts, const unsigned long long* __restrict__ rec,
            float* __restrict__ out, uint2* __restrict__ list,
            unsigned* __restrict__ cnt, unsigned segcap)
{
    __shared__ float s_wtot[4];
    __shared__ float s_skip[4];
    const int ray = blockIdx.x, t = threadIdx.x;
    const int lane = t & 63, w = t >> 6;
    const unsigned seg = (unsigned)blockIdx.x & (NSEG - 1u);

    float px = ray_pts[(ray * NSAMP + t) * 3 + 0];
    float py = ray_pts[(ray * NSAMP + t) * 3 + 1];
    float pz = ray_pts[(ray * NSAMP + t) * 3 + 2];
    float fx, fy, fz; int base;
    addr_calc(px, py, pz, fx, fy, fz, base);
    float wx0 = 1.f - fx, wy0 = 1.f - fy, wz0 = 1.f - fz;

    unsigned long long r8 = rec[base];      // one 8-B load: all 8 corner densities (fp8)
    unsigned lo = (unsigned)r8, hi = (unsigned)(r8 >> 32);
    float d000 = __builtin_amdgcn_cvt_f32_fp8((int)lo, 0);
    float d001 = __builtin_amdgcn_cvt_f32_fp8((int)lo, 1);
    float d010 = __builtin_amdgcn_cvt_f32_fp8((int)lo, 2);
    float d011 = __builtin_amdgcn_cvt_f32_fp8((int)lo, 3);
    float d100 = __builtin_amdgcn_cvt_f32_fp8((int)hi, 0);
    float d101 = __builtin_amdgcn_cvt_f32_fp8((int)hi, 1);
    float d110 = __builtin_amdgcn_cvt_f32_fp8((int)hi, 2);
    float d111 = __builtin_amdgcn_cvt_f32_fp8((int)hi, 3);
    float w00 = wx0 * wy0, w01 = wx0 * fy, w10 = fx * wy0, w11 = fx * fy;
    float dens =
        (d000 * wz0 + d001 * fz) * w00 +
        (d010 * wz0 + d011 * fz) * w01 +
        (d100 * wz0 + d101 * fz) * w10 +
        (d110 * wz0 + d111 * fz) * w11;

    float sv    = dens + ACT_SHIFT;
    float rs    = rsqrtf(1.0f + __expf(sv));
    float alpha = 1.0f - rs;
    float x     = rs + EPSF;                // 1 - alpha + EPS
    #pragma unroll
    for (int off = 1; off < 64; off <<= 1) {
        float y = __shfl_up(x, off);
        if (lane >= off) x *= y;
    }
    if (lane == 63) s_wtot[w] = x;
    __syncthreads();
    float t0 = s_wtot[0], t1 = s_wtot[1], t2 = s_wtot[2], t3 = s_wtot[3];
    float pre = 1.f;
    if (w > 0) pre *= t0;
    if (w > 1) pre *= t1;
    if (w > 2) pre *= t2;
    const float ainv = t0 * t1 * t2 * t3;
    float ex = __shfl_up(x, 1);
    if (lane == 0) ex = 1.f;
    const float wgt = alpha * ex * pre;

    // ---- cull + wave compaction (per-segment counter) ----
    bool keep = wgt > TAU;
    unsigned long long mask = __ballot(keep);
    int n = __popcll(mask);
    unsigned bslot = 0;
    if (lane == 0 && n) bslot = atomicAdd(cnt + seg * CSTR, (unsigned)n);
    bslot = (unsigned)__shfl((int)bslot, 0);
    int off2 = __popcll(mask & ((1ull << lane) - 1ull));
    unsigned slot = bslot + (unsigned)off2;
    bool kept = keep && (slot < segcap);
    if (kept) list[(size_t)seg * segcap + slot] =
        make_uint2((unsigned)(ray * NSAMP + t), __float_as_uint(wgt));

    // skipped samples contribute 0.5*wgt (rgb ~ 0.5); bound 0.5*256*TAU
    float skipw = kept ? 0.f : wgt;
    #pragma unroll
    for (int o = 32; o > 0; o >>= 1) skipw += __shfl_down(skipw, o);
    if (lane == 0) s_skip[w] = skipw;
    __syncthreads();
    if (t == 0) {
        float o = ainv + 0.5f * (s_skip[0] + s_skip[1] + s_skip[2] + s_skip[3]);
        out[ray * 3 + 0] = o; out[ray * 3 + 1] = o; out[ray * 3 + 2] = o;
    }
}

// ---------- K3: sparse pass — fp8 MFMA MLP over the 64 compacted sub-lists ----------
__global__ __launch_bounds__(256)
void pass_b(const float* __restrict__ ray_pts, const float* __restrict__ viewdirs,
            const float* __restrict__ k0,
            const float* __restrict__ w0, const float* __restrict__ b0,
            const float* __restrict__ w1, const float* __restrict__ b1,
            const float* __restrict__ w2, const float* __restrict__ b2,
            const uint2* __restrict__ list, const unsigned* __restrict__ cntp,
            unsigned segcap, float* __restrict__ out)
{
    __shared__ __align__(16) unsigned char s_w1a[HID * W1P8];
    __shared__ __align__(16) unsigned char s_w0a[HID * W0P8];
    __shared__ __align__(16) float4 s_w2b[HID];
    __shared__ unsigned s_pre[NSEG + 1];    // exclusive prefix of per-segment counts
    const int t = threadIdx.x, lane = t & 63, wv = t >> 6;
    const int nidx = lane & 31, qh = lane >> 5;

    for (int e = t; e < HID * HID; e += 256) {
        int i = e >> 7, o = e & 127;
        s_w1a[o * W1P8 + i] = fp8b(w1[e]);
    }
    for (int e = t; e < 39 * HID; e += 256) {
        int i = e >> 7, o = e & 127;
        s_w0a[o * W0P8 + i] = fp8b(w0[e]);
    }
    if (t < HID) {
        s_w0a[t * W0P8 + 39] = fp8b(b0[t]);   // bias via ones-entry (k=39)
        #pragma unroll
        for (int i = 40; i < 48; ++i) s_w0a[t * W0P8 + i] = 0;
        s_w2b[t] = make_float4(w2[t * 3 + 0], w2[t * 3 + 1], w2[t * 3 + 2], b1[t]);
    }
    if (t == 0) {
        unsigned acc = 0;
        s_pre[0] = 0;
        #pragma unroll 4
        for (int s = 0; s < NSEG; ++s) {
            unsigned n = cntp[s * CSTR];
            if (n > segcap) n = segcap;
            acc += n;
            s_pre[s + 1] = acc;
        }
    }
    const float b2x = b2[0], b2y = b2[1], b2z = b2[2];
    __syncthreads();

    const unsigned total = s_pre[NSEG];
    const unsigned stride = gridDim.x * 4 * 64;

    for (unsigned ib = (blockIdx.x * 4 + wv) * 64; ib < total; ib += stride) {
        unsigned i = ib + (unsigned)lane;
        uint2 e = make_uint2(0u, 0u);
        if (i < total) {
            // map flat index -> (segment, local) via 6-step binary search in LDS
            int lo = 0, hi = NSEG;
            #pragma unroll
            for (int st = 0; st < 6; ++st) {
                int mid = (lo + hi) >> 1;
                if (i >= s_pre[mid]) lo = mid; else hi = mid;
            }
            e = list[(size_t)lo * segcap + (i - s_pre[lo])];
        }
        float wgt = __uint_as_float(e.y);       // 0 for tail lanes
        unsigned sid = e.x;
        unsigned ray = sid >> 8;

        // ---- raw fp32 feat gather (tiny count) ----
        float px = ray_pts[sid * 3 + 0];
        float py = ray_pts[sid * 3 + 1];
        float pz = ray_pts[sid * 3 + 2];
        float fx, fy, fz; int base;
        addr_calc(px, py, pz, fx, fy, fz, base);
        float wxa[2] = {1.f - fx, fx}, wya[2] = {1.f - fy, fy}, wza[2] = {1.f - fz, fz};
        float feat[CF];
        #pragma unroll
        for (int c = 0; c < CF; ++c) feat[c] = 0.f;
        #pragma unroll
        for (int dx = 0; dx < 2; ++dx)
        #pragma unroll
        for (int dy = 0; dy < 2; ++dy)
        #pragma unroll
        for (int dz = 0; dz < 2; ++dz) {
            int idx = base + dx * (GD * GD) + dy * GD + dz;
            float wc = wxa[dx] * wya[dy] * wza[dz];
            const float4* kp = (const float4*)(k0 + (long)idx * CF);
            float4 a = kp[0], b = kp[1], c = kp[2];
            feat[0]  = fmaf(a.x, wc, feat[0]);  feat[1]  = fmaf(a.y, wc, feat[1]);
            feat[2]  = fmaf(a.z, wc, feat[2]);  feat[3]  = fmaf(a.w, wc, feat[3]);
            feat[4]  = fmaf(b.x, wc, feat[4]);  feat[5]  = fmaf(b.y, wc, feat[5]);
            feat[6]  = fmaf(b.z, wc, feat[6]);  feat[7]  = fmaf(b.w, wc, feat[7]);
            feat[8]  = fmaf(c.x, wc, feat[8]);  feat[9]  = fmaf(c.y, wc, feat[9]);
            feat[10] = fmaf(c.z, wc, feat[10]); feat[11] = fmaf(c.w, wc, feat[11]);
        }

        // ---- per-sample view embedding ----
        float vx = viewdirs[ray * 3 + 0], vy = viewdirs[ray * 3 + 1], vz = viewdirs[ray * 3 + 2];
        float inv = 1.0f / (sqrtf(vx * vx + vy * vy + vz * vz) + EPSF);
        float ve[27];
        ve[0] = vx * inv; ve[1] = vy * inv; ve[2] = vz * inv;
        #pragma unroll
        for (int ii = 0; ii < 3; ++ii)
            #pragma unroll
            for (int f = 0; f < 4; ++f) {
                float ang = ve[ii] * (float)(1 << f);
                ve[3  + ii * 4 + f] = __sinf(ang);
                ve[15 + ii * 4 + f] = __cosf(ang);
            }
        // k-stream fp8 dwords d0..d11 (k0..47): feats, vemb, 1.0 at k39, zeros
        unsigned d[12];
        d[0] = pk4(feat[0], feat[1], feat[2],  feat[3]);
        d[1] = pk4(feat[4], feat[5], feat[6],  feat[7]);
        d[2] = pk4(feat[8], feat[9], feat[10], feat[11]);
        #pragma unroll
        for (int q = 0; q < 6; ++q)
            d[3 + q] = pk4(ve[4*q], ve[4*q+1], ve[4*q+2], ve[4*q+3]);
        d[9] = pk4(ve[24], ve[25], ve[26], 1.0f);
        d[10] = 0u; d[11] = 0u;

        // ---- layer0 B-frags via shuffles (per-sample everything) ----
        long long bk[2][3];
        #pragma unroll
        for (int nt = 0; nt < 2; ++nt) {
            int src = nt * 32 + nidx;
            #pragma unroll
            for (int kt = 0; kt < 3; ++kt) {
                unsigned a0 = __shfl(d[4*kt+0], src), a1 = __shfl(d[4*kt+1], src);
                unsigned a2 = __shfl(d[4*kt+2], src), a3 = __shfl(d[4*kt+3], src);
                bk[nt][kt] = qh ? mk64(a2, a3) : mk64(a0, a1);
            }
        }

        // ---- layer0 MFMA + relu + fp8 repack ----
        unsigned p4A[4][4], p4B[4][4];
        #pragma unroll
        for (int mt = 0; mt < 4; ++mt) {
            f32x16 aA = {}, aB = {};
            const unsigned char* w0row = &s_w0a[(nidx + mt * 32) * W0P8 + qh * 8];
            #pragma unroll
            for (int kk = 0; kk < 3; ++kk) {
                long long af = *(const long long*)(w0row + kk * 16);
                aA = __builtin_amdgcn_mfma_f32_32x32x16_fp8_fp8(af, bk[0][kk], aA, 0, 0, 0);
                aB = __builtin_amdgcn_mfma_f32_32x32x16_fp8_fp8(af, bk[1][kk], aB, 0, 0, 0);
            }
            #pragma unroll
            for (int q = 0; q < 4; ++q) {
                p4A[mt][q] = pk4(fmaxf(aA[4*q+0], 0.f), fmaxf(aA[4*q+1], 0.f),
                                 fmaxf(aA[4*q+2], 0.f), fmaxf(aA[4*q+3], 0.f));
                p4B[mt][q] = pk4(fmaxf(aB[4*q+0], 0.f), fmaxf(aB[4*q+1], 0.f),
                                 fmaxf(aB[4*q+2], 0.f), fmaxf(aB[4*q+3], 0.f));
            }
        }

        // ---- C->B transition ----
        long long hfA[8], hfB[8];
        #pragma unroll
        for (int kt = 0; kt < 8; ++kt) {
            const int mt = kt >> 1, b = kt & 1;
            unsigned srcA = qh ? p4A[mt][2*b+1] : p4A[mt][2*b];
            unsigned srcB = qh ? p4B[mt][2*b+1] : p4B[mt][2*b];
            hfA[kt] = mk64(__shfl(srcA, nidx), __shfl(srcA, nidx + 32));
            hfB[kt] = mk64(__shfl(srcB, nidx), __shfl(srcB, nidx + 32));
        }

        // ---- layer1 MFMA + layer2 ----
        float rA0 = 0.f, rA1 = 0.f, rA2 = 0.f;
        float rB0 = 0.f, rB1 = 0.f, rB2 = 0.f;
        #pragma unroll
        for (int mt2 = 0; mt2 < 4; ++mt2) {
            f32x16 cA = {}, cB = {};
            const unsigned char* w1row = &s_w1a[(nidx + mt2 * 32) * W1P8 + qh * 8];
            #pragma unroll
            for (int kt = 0; kt < 8; ++kt) {
                long long af = *(const long long*)(w1row + kt * 16);
                cA = __builtin_amdgcn_mfma_f32_32x32x16_fp8_fp8(af, hfA[kt], cA, 0, 0, 0);
                cB = __builtin_amdgcn_mfma_f32_32x32x16_fp8_fp8(af, hfB[kt], cB, 0, 0, 0);
            }
            #pragma unroll
            for (int reg = 0; reg < 16; ++reg) {
                int dim = mt2 * 32 + (reg & 3) + 8 * (reg >> 2) + 4 * qh;
                float4 wb = s_w2b[dim];
                float hvA = fmaxf(cA[reg] + wb.w, 0.f);
                rA0 = fmaf(hvA, wb.x, rA0); rA1 = fmaf(hvA, wb.y, rA1); rA2 = fmaf(hvA, wb.z, rA2);
                float hvB = fmaxf(cB[reg] + wb.w, 0.f);
                rB0 = fmaf(hvB, wb.x, rB0); rB1 = fmaf(hvB, wb.y, rB1); rB2 = fmaf(hvB, wb.z, rB2);
            }
        }
        rA0 += __shfl_xor(rA0, 32); rA1 += __shfl_xor(rA1, 32); rA2 += __shfl_xor(rA2, 32);
        rB0 += __shfl_xor(rB0, 32); rB1 += __shfl_xor(rB1, 32); rB2 += __shfl_xor(rB2, 32);

        // per-sample scatter: qh==0 lanes own tile-A sample nidx, qh==1 own tile-B
        float wgtS; unsigned sidS; float r0, r1, r2;
        if (qh == 0) {
            wgtS = __shfl(wgt, nidx);          sidS = (unsigned)__shfl((int)sid, nidx);
            r0 = rA0; r1 = rA1; r2 = rA2;
        } else {
            wgtS = __shfl(wgt, nidx + 32);     sidS = (unsigned)__shfl((int)sid, nidx + 32);
            r0 = rB0; r1 = rB1; r2 = rB2;
        }
        if (wgtS != 0.f) {
            unsigned rs_ = sidS >> 8;
            float c0 = wgtS * __builtin_amdgcn_rcpf(1.f + __expf(-(r0 + b2x)));
            float c1 = wgtS * __builtin_amdgcn_rcpf(1.f + __expf(-(r1 + b2y)));
            float c2 = wgtS * __builtin_amdgcn_rcpf(1.f + __expf(-(r2 + b2z)));
            atomicAdd(&out[rs_ * 3 + 0], c0);
            atomicAdd(&out[rs_ * 3 + 1], c1);
            atomicAdd(&out[rs_ * 3 + 2], c2);
        }
    }
}

// ---------- emergency fallback (ws too small): density-only, rgb ~ 0.5 ----------
__global__ __launch_bounds__(256)
void dvgo_fallback(const float* __restrict__ ray_pts, const float* __restrict__ dg,
                   float* __restrict__ out)
{
    __shared__ float s_wtot[4];
    __shared__ float s_sum[4];
    const int ray = blockIdx.x, t = threadIdx.x;
    const int lane = t & 63, w = t >> 6;
    float px = ray_pts[(ray * NSAMP + t) * 3 + 0];
    float py = ray_pts[(ray * NSAMP + t) * 3 + 1];
    float pz = ray_pts[(ray * NSAMP + t) * 3 + 2];
    float fx, fy, fz; int base;
    addr_calc(px, py, pz, fx, fy, fz, base);
    float wxa[2] = {1.f - fx, fx}, wya[2] = {1.f - fy, fy}, wza[2] = {1.f - fz, fz};
    float dens = 0.f;
    #pragma unroll
    for (int dx = 0; dx < 2; ++dx)
    #pragma unroll
    for (int dy = 0; dy < 2; ++dy)
    #pragma unroll
    for (int dz = 0; dz < 2; ++dz)
        dens = fmaf(dg[base + dx*(GD*GD) + dy*GD + dz], wxa[dx]*wya[dy]*wza[dz], dens);
    float rs = rsqrtf(1.0f + __expf(dens + ACT_SHIFT));
    float alpha = 1.0f - rs;
    float x = rs + EPSF;
    #pragma unroll
    for (int off = 1; off < 64; off <<= 1) {
        float y = __shfl_up(x, off);
        if (lane >= off) x *= y;
    }
    if (lane == 63) s_wtot[w] = x;
    __syncthreads();
    float t0 = s_wtot[0], t1 = s_wtot[1], t2 = s_wtot[2], t3 = s_wtot[3];
    float pre = 1.f;
    if (w > 0) pre *= t0;
    if (w > 1) pre *= t1;
    if (w > 2) pre *= t2;
    float ainv = t0 * t1 * t2 * t3;
    float ex = __shfl_up(x, 1);
    if (lane == 0) ex = 1.f;
    float wgt = alpha * ex * pre;
    #pragma unroll
    for (int o = 32; o > 0; o >>= 1) wgt += __shfl_down(wgt, o);
    if (lane == 0) s_sum[w] = wgt;
    __syncthreads();
    if (t == 0) {
        float o = ainv + 0.5f * (s_sum[0] + s_sum[1] + s_sum[2] + s_sum[3]);
        out[ray * 3 + 0] = o; out[ray * 3 + 1] = o; out[ray * 3 + 2] = o;
    }
}

extern "C" void kernel_launch(void* const* d_in, const int* in_sizes, int n_in,
                              void* d_out, int out_size, void* d_ws, size_t ws_size,
                              hipStream_t stream) {
    const float* ray_pts      = (const float*)d_in[0];
    const float* viewdirs     = (const float*)d_in[1];
    const float* density_grid = (const float*)d_in[2];
    const float* k0           = (const float*)d_in[3];
    const float* w0           = (const float*)d_in[4];
    const float* b0           = (const float*)d_in[5];
    const float* w1           = (const float*)d_in[6];
    const float* b1           = (const float*)d_in[7];
    const float* w2           = (const float*)d_in[8];
    const float* b2           = (const float*)d_in[9];
    float*       outp         = (float*)d_out;

    const size_t min_ws = WS_LIST_OFF + (size_t)65536 * 8;   // records + minimal list
    if (ws_size >= min_ws) {
        unsigned*           cnt  = (unsigned*)d_ws;
        unsigned long long* rec  = (unsigned long long*)((char*)d_ws + WS_REC_OFF);
        uint2*              list = (uint2*)((char*)d_ws + WS_LIST_OFF);
        size_t cap_sz = (ws_size - WS_LIST_OFF) / 8;
        size_t sc = cap_sz / NSEG;
        unsigned segcap = (unsigned)((sc > (size_t)32768) ? (size_t)32768 : sc);  // 128 rays/seg * 256 max

        prep_rec8<<<dim3(GD, GD), dim3(GD), 0, stream>>>(density_grid, rec, cnt);
        pass_a<<<dim3(NRAYS), dim3(NSAMP), 0, stream>>>(ray_pts, rec, outp, list, cnt, segcap);
        pass_b<<<dim3(256), dim3(256), 0, stream>>>(ray_pts, viewdirs, k0,
                                                    w0, b0, w1, b1, w2, b2,
                                                    list, cnt, segcap, outp);
    } else {
        dvgo_fallback<<<dim3(NRAYS), dim3(NSAMP), 0, stream>>>(ray_pts, density_grid, outp);
    }
}

// Round 5
// 352.484 us; speedup vs baseline: 1.2312x; 1.0241x over previous
//
#include <hip/hip_runtime.h>
#include <math.h>

#define NRAYS 8192
#define NSAMP 256
#define GD    160
#define NVOX  (GD*GD*GD)
#define CF    12
#define HID   128
#define W0P8  56            // s_w0a row pitch BYTES (48 data + 8 pad)
#define W1P8  136           // s_w1a row pitch BYTES (128 data + 8 pad)
#define TAU   1e-5f         // weight cull: err <= 0.5*256*TAU = 1.28e-3 < 2e-2 tol (15x margin)
#define NSEG  64            // reservation-counter segments (kills same-address atomic serialization)
#define CSTR  64            // counter stride in u32 (256 B apart -> distinct lines/channels)

// ws layout: [cnt u32 x64, 256B apart -> 16 KB] [fp8 corner records 8B*NVOX = 32.8 MB] [segmented entry lists]
// ONE 8-B gather per sample: R3 proved pass_a is TRANSACTION-bound (4x4B gathers -> +69us),
// R4 proved it is not byte-bound (16B->8B recs -> only -4us). So: minimize divergent
// transactions, then maximize memory-level parallelism (2 rays/block below).
#define WS_REC_OFF  ((size_t)16384)
#define WS_LIST_OFF (WS_REC_OFF + (size_t)NVOX * 8)

static constexpr float ACT_SHIFT = -13.815509557963774f;
static constexpr float EPSF      = 1e-10f;

typedef __attribute__((ext_vector_type(16))) float f32x16;

__device__ __forceinline__ unsigned pk4(float a, float b, float c, float d) {
    int u = __builtin_amdgcn_cvt_pk_fp8_f32(a, b, 0, false);
    u     = __builtin_amdgcn_cvt_pk_fp8_f32(c, d, u, true);
    return (unsigned)u;
}
__device__ __forceinline__ unsigned char fp8b(float x) {
    return (unsigned char)(__builtin_amdgcn_cvt_pk_fp8_f32(x, x, 0, false) & 0xff);
}
__device__ __forceinline__ long long mk64(unsigned lo, unsigned hi) {
    return (long long)(((unsigned long long)hi << 32) | (unsigned long long)lo);
}

__device__ __forceinline__ void addr_calc(float px, float py, float pz,
                                          float& fx, float& fy, float& fz, int& base) {
    px = fminf(fmaxf(px, 0.f), 1.f) * (float)(GD - 1);
    py = fminf(fmaxf(py, 0.f), 1.f) * (float)(GD - 1);
    pz = fminf(fmaxf(pz, 0.f), 1.f) * (float)(GD - 1);
    int ix = min((int)px, GD - 2);
    int iy = min((int)py, GD - 2);
    int iz = min((int)pz, GD - 2);
    fx = px - (float)ix; fy = py - (float)iy; fz = pz - (float)iz;
    base = (ix * GD + iy) * GD + iz;
}

__device__ __forceinline__ float dens8(unsigned long long r8,
                                       float fx, float fy, float fz) {
    unsigned lo = (unsigned)r8, hi = (unsigned)(r8 >> 32);
    float wx0 = 1.f - fx, wy0 = 1.f - fy, wz0 = 1.f - fz;
    float d000 = __builtin_amdgcn_cvt_f32_fp8((int)lo, 0);
    float d001 = __builtin_amdgcn_cvt_f32_fp8((int)lo, 1);
    float d010 = __builtin_amdgcn_cvt_f32_fp8((int)lo, 2);
    float d011 = __builtin_amdgcn_cvt_f32_fp8((int)lo, 3);
    float d100 = __builtin_amdgcn_cvt_f32_fp8((int)hi, 0);
    float d101 = __builtin_amdgcn_cvt_f32_fp8((int)hi, 1);
    float d110 = __builtin_amdgcn_cvt_f32_fp8((int)hi, 2);
    float d111 = __builtin_amdgcn_cvt_f32_fp8((int)hi, 3);
    float w00 = wx0 * wy0, w01 = wx0 * fy, w10 = fx * wy0, w11 = fx * fy;
    return (d000 * wz0 + d001 * fz) * w00 +
           (d010 * wz0 + d011 * fz) * w01 +
           (d100 * wz0 + d101 * fz) * w10 +
           (d110 * wz0 + d111 * fz) * w11;
}

// ---------- K1: density -> replicated 2x2x2 fp8 corner records (8 B/cell) ----------
// byte c = corner (dx*4 + dy*2 + dz). Also zeroes the 64 segment counters (block 0).
__global__ __launch_bounds__(256)
void prep_rec8(const float* __restrict__ dg, unsigned long long* __restrict__ rec,
               unsigned* __restrict__ cnt)
{
    int iz = threadIdx.x;            // 0..159
    int iy = blockIdx.x;
    int ix = blockIdx.y;
    if (iy == 0 && ix == 0 && iz < NSEG) cnt[iz * CSTR] = 0;   // merged memset
    int xp = min(ix + 1, GD - 1), yp = min(iy + 1, GD - 1), zp = min(iz + 1, GD - 1);
    int r00 = (ix * GD + iy) * GD, r01 = (ix * GD + yp) * GD;
    int r10 = (xp * GD + iy) * GD, r11 = (xp * GD + yp) * GD;
    unsigned lo = pk4(dg[r00 + iz], dg[r00 + zp], dg[r01 + iz], dg[r01 + zp]);
    unsigned hi = pk4(dg[r10 + iz], dg[r10 + zp], dg[r11 + iz], dg[r11 + zp]);
    rec[(ix * GD + iy) * GD + iz] = ((unsigned long long)hi << 32) | (unsigned long long)lo;
}

// ---------- K2: dense pass — 2 rays/block for 2x memory-level parallelism ----------
// Each thread owns sample t of ray 2b AND ray 2b+1: two independent 8-B gathers in
// flight (latency-bound gather -> ~2x), two interleaved shfl scans (latency overlapped).
__global__ __launch_bounds__(256)
void pass_a(const float* __restrict__ ray_pts, const unsigned long long* __restrict__ rec,
            float* __restrict__ out, uint2* __restrict__ list,
            unsigned* __restrict__ cnt, unsigned segcap)
{
    __shared__ float s_wtot[2][4];
    __shared__ float s_skip[2][4];
    const int t = threadIdx.x;
    const int lane = t & 63, w = t >> 6;
    const int r0 = blockIdx.x * 2, r1 = r0 + 1;
    const unsigned seg = (unsigned)blockIdx.x & (NSEG - 1u);

    const int sid0 = r0 * NSAMP + t, sid1 = r1 * NSAMP + t;
    float px0 = ray_pts[sid0 * 3 + 0], py0 = ray_pts[sid0 * 3 + 1], pz0 = ray_pts[sid0 * 3 + 2];
    float px1 = ray_pts[sid1 * 3 + 0], py1 = ray_pts[sid1 * 3 + 1], pz1 = ray_pts[sid1 * 3 + 2];
    float fx0, fy0, fz0, fx1, fy1, fz1; int base0, base1;
    addr_calc(px0, py0, pz0, fx0, fy0, fz0, base0);
    addr_calc(px1, py1, pz1, fx1, fy1, fz1, base1);

    unsigned long long g0 = rec[base0];     // two independent gathers, ILP-2
    unsigned long long g1 = rec[base1];
    float den0 = dens8(g0, fx0, fy0, fz0);
    float den1 = dens8(g1, fx1, fy1, fz1);

    float rs0 = rsqrtf(1.0f + __expf(den0 + ACT_SHIFT));
    float rs1 = rsqrtf(1.0f + __expf(den1 + ACT_SHIFT));
    float alpha0 = 1.0f - rs0, alpha1 = 1.0f - rs1;
    float x0 = rs0 + EPSF, x1 = rs1 + EPSF;   // 1 - alpha + EPS
    #pragma unroll
    for (int off = 1; off < 64; off <<= 1) {
        float y0 = __shfl_up(x0, off);
        float y1 = __shfl_up(x1, off);
        if (lane >= off) { x0 *= y0; x1 *= y1; }
    }
    if (lane == 63) { s_wtot[0][w] = x0; s_wtot[1][w] = x1; }
    __syncthreads();
    float t00 = s_wtot[0][0], t01 = s_wtot[0][1], t02 = s_wtot[0][2], t03 = s_wtot[0][3];
    float t10 = s_wtot[1][0], t11 = s_wtot[1][1], t12 = s_wtot[1][2], t13 = s_wtot[1][3];
    float pre0 = 1.f, pre1 = 1.f;
    if (w > 0) { pre0 *= t00; pre1 *= t10; }
    if (w > 1) { pre0 *= t01; pre1 *= t11; }
    if (w > 2) { pre0 *= t02; pre1 *= t12; }
    const float ainv0 = t00 * t01 * t02 * t03;
    const float ainv1 = t10 * t11 * t12 * t13;
    float ex0 = __shfl_up(x0, 1), ex1 = __shfl_up(x1, 1);
    if (lane == 0) { ex0 = 1.f; ex1 = 1.f; }
    const float wgt0 = alpha0 * ex0 * pre0;
    const float wgt1 = alpha1 * ex1 * pre1;

    // ---- cull + wave compaction (one reservation for both rays) ----
    bool keep0 = wgt0 > TAU, keep1 = wgt1 > TAU;
    unsigned long long mask0 = __ballot(keep0);
    unsigned long long mask1 = __ballot(keep1);
    int n0 = __popcll(mask0), n1 = __popcll(mask1);
    unsigned bslot = 0;
    if (lane == 0 && (n0 + n1)) bslot = atomicAdd(cnt + seg * CSTR, (unsigned)(n0 + n1));
    bslot = (unsigned)__shfl((int)bslot, 0);
    unsigned long long lmask = (1ull << lane) - 1ull;
    unsigned slot0 = bslot + (unsigned)__popcll(mask0 & lmask);
    unsigned slot1 = bslot + (unsigned)n0 + (unsigned)__popcll(mask1 & lmask);
    bool kept0 = keep0 && (slot0 < segcap);
    bool kept1 = keep1 && (slot1 < segcap);
    if (kept0) list[(size_t)seg * segcap + slot0] = make_uint2((unsigned)sid0, __float_as_uint(wgt0));
    if (kept1) list[(size_t)seg * segcap + slot1] = make_uint2((unsigned)sid1, __float_as_uint(wgt1));

    // skipped samples contribute 0.5*wgt (rgb ~ 0.5); bound 0.5*256*TAU per ray
    float sk0 = kept0 ? 0.f : wgt0;
    float sk1 = kept1 ? 0.f : wgt1;
    #pragma unroll
    for (int o = 32; o > 0; o >>= 1) {
        sk0 += __shfl_down(sk0, o);
        sk1 += __shfl_down(sk1, o);
    }
    if (lane == 0) { s_skip[0][w] = sk0; s_skip[1][w] = sk1; }
    __syncthreads();
    if (t == 0) {
        float o0 = ainv0 + 0.5f * (s_skip[0][0] + s_skip[0][1] + s_skip[0][2] + s_skip[0][3]);
        float o1 = ainv1 + 0.5f * (s_skip[1][0] + s_skip[1][1] + s_skip[1][2] + s_skip[1][3]);
        out[r0 * 3 + 0] = o0; out[r0 * 3 + 1] = o0; out[r0 * 3 + 2] = o0;
        out[r1 * 3 + 0] = o1; out[r1 * 3 + 1] = o1; out[r1 * 3 + 2] = o1;
    }
}

// ---------- K3: sparse pass — fp8 MFMA MLP over the 64 compacted sub-lists ----------
__global__ __launch_bounds__(256)
void pass_b(const float* __restrict__ ray_pts, const float* __restrict__ viewdirs,
            const float* __restrict__ k0,
            const float* __restrict__ w0, const float* __restrict__ b0,
            const float* __restrict__ w1, const float* __restrict__ b1,
            const float* __restrict__ w2, const float* __restrict__ b2,
            const uint2* __restrict__ list, const unsigned* __restrict__ cntp,
            unsigned segcap, float* __restrict__ out)
{
    __shared__ __align__(16) unsigned char s_w1a[HID * W1P8];
    __shared__ __align__(16) unsigned char s_w0a[HID * W0P8];
    __shared__ __align__(16) float4 s_w2b[HID];
    __shared__ unsigned s_pre[NSEG + 1];    // exclusive prefix of per-segment counts
    const int t = threadIdx.x, lane = t & 63, wv = t >> 6;
    const int nidx = lane & 31, qh = lane >> 5;

    for (int e = t; e < HID * HID; e += 256) {
        int i = e >> 7, o = e & 127;
        s_w1a[o * W1P8 + i] = fp8b(w1[e]);
    }
    for (int e = t; e < 39 * HID; e += 256) {
        int i = e >> 7, o = e & 127;
        s_w0a[o * W0P8 + i] = fp8b(w0[e]);
    }
    if (t < HID) {
        s_w0a[t * W0P8 + 39] = fp8b(b0[t]);   // bias via ones-entry (k=39)
        #pragma unroll
        for (int i = 40; i < 48; ++i) s_w0a[t * W0P8 + i] = 0;
        s_w2b[t] = make_float4(w2[t * 3 + 0], w2[t * 3 + 1], w2[t * 3 + 2], b1[t]);
    }
    if (t == 0) {
        unsigned acc = 0;
        s_pre[0] = 0;
        #pragma unroll 4
        for (int s = 0; s < NSEG; ++s) {
            unsigned n = cntp[s * CSTR];
            if (n > segcap) n = segcap;
            acc += n;
            s_pre[s + 1] = acc;
        }
    }
    const float b2x = b2[0], b2y = b2[1], b2z = b2[2];
    __syncthreads();

    const unsigned total = s_pre[NSEG];
    const unsigned stride = gridDim.x * 4 * 64;

    for (unsigned ib = (blockIdx.x * 4 + wv) * 64; ib < total; ib += stride) {
        unsigned i = ib + (unsigned)lane;
        uint2 e = make_uint2(0u, 0u);
        if (i < total) {
            // map flat index -> (segment, local) via 6-step binary search in LDS
            int lo = 0, hi = NSEG;
            #pragma unroll
            for (int st = 0; st < 6; ++st) {
                int mid = (lo + hi) >> 1;
                if (i >= s_pre[mid]) lo = mid; else hi = mid;
            }
            e = list[(size_t)lo * segcap + (i - s_pre[lo])];
        }
        float wgt = __uint_as_float(e.y);       // 0 for tail lanes
        unsigned sid = e.x;
        unsigned ray = sid >> 8;

        // ---- raw fp32 feat gather (tiny count) ----
        float px = ray_pts[sid * 3 + 0];
        float py = ray_pts[sid * 3 + 1];
        float pz = ray_pts[sid * 3 + 2];
        float fx, fy, fz; int base;
        addr_calc(px, py, pz, fx, fy, fz, base);
        float wxa[2] = {1.f - fx, fx}, wya[2] = {1.f - fy, fy}, wza[2] = {1.f - fz, fz};
        float feat[CF];
        #pragma unroll
        for (int c = 0; c < CF; ++c) feat[c] = 0.f;
        #pragma unroll
        for (int dx = 0; dx < 2; ++dx)
        #pragma unroll
        for (int dy = 0; dy < 2; ++dy)
        #pragma unroll
        for (int dz = 0; dz < 2; ++dz) {
            int idx = base + dx * (GD * GD) + dy * GD + dz;
            float wc = wxa[dx] * wya[dy] * wza[dz];
            const float4* kp = (const float4*)(k0 + (long)idx * CF);
            float4 a = kp[0], b = kp[1], c = kp[2];
            feat[0]  = fmaf(a.x, wc, feat[0]);  feat[1]  = fmaf(a.y, wc, feat[1]);
            feat[2]  = fmaf(a.z, wc, feat[2]);  feat[3]  = fmaf(a.w, wc, feat[3]);
            feat[4]  = fmaf(b.x, wc, feat[4]);  feat[5]  = fmaf(b.y, wc, feat[5]);
            feat[6]  = fmaf(b.z, wc, feat[6]);  feat[7]  = fmaf(b.w, wc, feat[7]);
            feat[8]  = fmaf(c.x, wc, feat[8]);  feat[9]  = fmaf(c.y, wc, feat[9]);
            feat[10] = fmaf(c.z, wc, feat[10]); feat[11] = fmaf(c.w, wc, feat[11]);
        }

        // ---- per-sample view embedding ----
        float vx = viewdirs[ray * 3 + 0], vy = viewdirs[ray * 3 + 1], vz = viewdirs[ray * 3 + 2];
        float inv = 1.0f / (sqrtf(vx * vx + vy * vy + vz * vz) + EPSF);
        float ve[27];
        ve[0] = vx * inv; ve[1] = vy * inv; ve[2] = vz * inv;
        #pragma unroll
        for (int ii = 0; ii < 3; ++ii)
            #pragma unroll
            for (int f = 0; f < 4; ++f) {
                float ang = ve[ii] * (float)(1 << f);
                ve[3  + ii * 4 + f] = __sinf(ang);
                ve[15 + ii * 4 + f] = __cosf(ang);
            }
        // k-stream fp8 dwords d0..d11 (k0..47): feats, vemb, 1.0 at k39, zeros
        unsigned d[12];
        d[0] = pk4(feat[0], feat[1], feat[2],  feat[3]);
        d[1] = pk4(feat[4], feat[5], feat[6],  feat[7]);
        d[2] = pk4(feat[8], feat[9], feat[10], feat[11]);
        #pragma unroll
        for (int q = 0; q < 6; ++q)
            d[3 + q] = pk4(ve[4*q], ve[4*q+1], ve[4*q+2], ve[4*q+3]);
        d[9] = pk4(ve[24], ve[25], ve[26], 1.0f);
        d[10] = 0u; d[11] = 0u;

        // ---- layer0 B-frags via shuffles (per-sample everything) ----
        long long bk[2][3];
        #pragma unroll
        for (int nt = 0; nt < 2; ++nt) {
            int src = nt * 32 + nidx;
            #pragma unroll
            for (int kt = 0; kt < 3; ++kt) {
                unsigned a0 = __shfl(d[4*kt+0], src), a1 = __shfl(d[4*kt+1], src);
                unsigned a2 = __shfl(d[4*kt+2], src), a3 = __shfl(d[4*kt+3], src);
                bk[nt][kt] = qh ? mk64(a2, a3) : mk64(a0, a1);
            }
        }

        // ---- layer0 MFMA + relu + fp8 repack ----
        unsigned p4A[4][4], p4B[4][4];
        #pragma unroll
        for (int mt = 0; mt < 4; ++mt) {
            f32x16 aA = {}, aB = {};
            const unsigned char* w0row = &s_w0a[(nidx + mt * 32) * W0P8 + qh * 8];
            #pragma unroll
            for (int kk = 0; kk < 3; ++kk) {
                long long af = *(const long long*)(w0row + kk * 16);
                aA = __builtin_amdgcn_mfma_f32_32x32x16_fp8_fp8(af, bk[0][kk], aA, 0, 0, 0);
                aB = __builtin_amdgcn_mfma_f32_32x32x16_fp8_fp8(af, bk[1][kk], aB, 0, 0, 0);
            }
            #pragma unroll
            for (int q = 0; q < 4; ++q) {
                p4A[mt][q] = pk4(fmaxf(aA[4*q+0], 0.f), fmaxf(aA[4*q+1], 0.f),
                                 fmaxf(aA[4*q+2], 0.f), fmaxf(aA[4*q+3], 0.f));
                p4B[mt][q] = pk4(fmaxf(aB[4*q+0], 0.f), fmaxf(aB[4*q+1], 0.f),
                                 fmaxf(aB[4*q+2], 0.f), fmaxf(aB[4*q+3], 0.f));
            }
        }

        // ---- C->B transition ----
        long long hfA[8], hfB[8];
        #pragma unroll
        for (int kt = 0; kt < 8; ++kt) {
            const int mt = kt >> 1, b = kt & 1;
            unsigned srcA = qh ? p4A[mt][2*b+1] : p4A[mt][2*b];
            unsigned srcB = qh ? p4B[mt][2*b+1] : p4B[mt][2*b];
            hfA[kt] = mk64(__shfl(srcA, nidx), __shfl(srcA, nidx + 32));
            hfB[kt] = mk64(__shfl(srcB, nidx), __shfl(srcB, nidx + 32));
        }

        // ---- layer1 MFMA + layer2 ----
        float rA0 = 0.f, rA1 = 0.f, rA2 = 0.f;
        float rB0 = 0.f, rB1 = 0.f, rB2 = 0.f;
        #pragma unroll
        for (int mt2 = 0; mt2 < 4; ++mt2) {
            f32x16 cA = {}, cB = {};
            const unsigned char* w1row = &s_w1a[(nidx + mt2 * 32) * W1P8 + qh * 8];
            #pragma unroll
            for (int kt = 0; kt < 8; ++kt) {
                long long af = *(const long long*)(w1row + kt * 16);
                cA = __builtin_amdgcn_mfma_f32_32x32x16_fp8_fp8(af, hfA[kt], cA, 0, 0, 0);
                cB = __builtin_amdgcn_mfma_f32_32x32x16_fp8_fp8(af, hfB[kt], cB, 0, 0, 0);
            }
            #pragma unroll
            for (int reg = 0; reg < 16; ++reg) {
                int dim = mt2 * 32 + (reg & 3) + 8 * (reg >> 2) + 4 * qh;
                float4 wb = s_w2b[dim];
                float hvA = fmaxf(cA[reg] + wb.w, 0.f);
                rA0 = fmaf(hvA, wb.x, rA0); rA1 = fmaf(hvA, wb.y, rA1); rA2 = fmaf(hvA, wb.z, rA2);
                float hvB = fmaxf(cB[reg] + wb.w, 0.f);
                rB0 = fmaf(hvB, wb.x, rB0); rB1 = fmaf(hvB, wb.y, rB1); rB2 = fmaf(hvB, wb.z, rB2);
            }
        }
        rA0 += __shfl_xor(rA0, 32); rA1 += __shfl_xor(rA1, 32); rA2 += __shfl_xor(rA2, 32);
        rB0 += __shfl_xor(rB0, 32); rB1 += __shfl_xor(rB1, 32); rB2 += __shfl_xor(rB2, 32);

        // per-sample scatter: qh==0 lanes own tile-A sample nidx, qh==1 own tile-B
        float wgtS; unsigned sidS; float r0, r1, r2;
        if (qh == 0) {
            wgtS = __shfl(wgt, nidx);          sidS = (unsigned)__shfl((int)sid, nidx);
            r0 = rA0; r1 = rA1; r2 = rA2;
        } else {
            wgtS = __shfl(wgt, nidx + 32);     sidS = (unsigned)__shfl((int)sid, nidx + 32);
            r0 = rB0; r1 = rB1; r2 = rB2;
        }
        if (wgtS != 0.f) {
            unsigned rs_ = sidS >> 8;
            float c0 = wgtS * __builtin_amdgcn_rcpf(1.f + __expf(-(r0 + b2x)));
            float c1 = wgtS * __builtin_amdgcn_rcpf(1.f + __expf(-(r1 + b2y)));
            float c2 = wgtS * __builtin_amdgcn_rcpf(1.f + __expf(-(r2 + b2z)));
            atomicAdd(&out[rs_ * 3 + 0], c0);
            atomicAdd(&out[rs_ * 3 + 1], c1);
            atomicAdd(&out[rs_ * 3 + 2], c2);
        }
    }
}

// ---------- emergency fallback (ws too small): density-only, rgb ~ 0.5 ----------
__global__ __launch_bounds__(256)
void dvgo_fallback(const float* __restrict__ ray_pts, const float* __restrict__ dg,
                   float* __restrict__ out)
{
    __shared__ float s_wtot[4];
    __shared__ float s_sum[4];
    const int ray = blockIdx.x, t = threadIdx.x;
    const int lane = t & 63, w = t >> 6;
    float px = ray_pts[(ray * NSAMP + t) * 3 + 0];
    float py = ray_pts[(ray * NSAMP + t) * 3 + 1];
    float pz = ray_pts[(ray * NSAMP + t) * 3 + 2];
    float fx, fy, fz; int base;
    addr_calc(px, py, pz, fx, fy, fz, base);
    float wxa[2] = {1.f - fx, fx}, wya[2] = {1.f - fy, fy}, wza[2] = {1.f - fz, fz};
    float dens = 0.f;
    #pragma unroll
    for (int dx = 0; dx < 2; ++dx)
    #pragma unroll
    for (int dy = 0; dy < 2; ++dy)
    #pragma unroll
    for (int dz = 0; dz < 2; ++dz)
        dens = fmaf(dg[base + dx*(GD*GD) + dy*GD + dz], wxa[dx]*wya[dy]*wza[dz], dens);
    float rs = rsqrtf(1.0f + __expf(dens + ACT_SHIFT));
    float alpha = 1.0f - rs;
    float x = rs + EPSF;
    #pragma unroll
    for (int off = 1; off < 64; off <<= 1) {
        float y = __shfl_up(x, off);
        if (lane >= off) x *= y;
    }
    if (lane == 63) s_wtot[w] = x;
    __syncthreads();
    float t0 = s_wtot[0], t1 = s_wtot[1], t2 = s_wtot[2], t3 = s_wtot[3];
    float pre = 1.f;
    if (w > 0) pre *= t0;
    if (w > 1) pre *= t1;
    if (w > 2) pre *= t2;
    float ainv = t0 * t1 * t2 * t3;
    float ex = __shfl_up(x, 1);
    if (lane == 0) ex = 1.f;
    float wgt = alpha * ex * pre;
    #pragma unroll
    for (int o = 32; o > 0; o >>= 1) wgt += __shfl_down(wgt, o);
    if (lane == 0) s_sum[w] = wgt;
    __syncthreads();
    if (t == 0) {
        float o = ainv + 0.5f * (s_sum[0] + s_sum[1] + s_sum[2] + s_sum[3]);
        out[ray * 3 + 0] = o; out[ray * 3 + 1] = o; out[ray * 3 + 2] = o;
    }
}

extern "C" void kernel_launch(void* const* d_in, const int* in_sizes, int n_in,
                              void* d_out, int out_size, void* d_ws, size_t ws_size,
                              hipStream_t stream) {
    const float* ray_pts      = (const float*)d_in[0];
    const float* viewdirs     = (const float*)d_in[1];
    const float* density_grid = (const float*)d_in[2];
    const float* k0           = (const float*)d_in[3];
    const float* w0           = (const float*)d_in[4];
    const float* b0           = (const float*)d_in[5];
    const float* w1           = (const float*)d_in[6];
    const float* b1           = (const float*)d_in[7];
    const float* w2           = (const float*)d_in[8];
    const float* b2           = (const float*)d_in[9];
    float*       outp         = (float*)d_out;

    const size_t min_ws = WS_LIST_OFF + (size_t)65536 * 8;   // records + minimal list
    if (ws_size >= min_ws) {
        unsigned*           cnt  = (unsigned*)d_ws;
        unsigned long long* rec  = (unsigned long long*)((char*)d_ws + WS_REC_OFF);
        uint2*              list = (uint2*)((char*)d_ws + WS_LIST_OFF);
        size_t cap_sz = (ws_size - WS_LIST_OFF) / 8;
        size_t sc = cap_sz / NSEG;
        unsigned segcap = (unsigned)((sc > (size_t)32768) ? (size_t)32768 : sc);  // 128 rays/seg * 256 max

        prep_rec8<<<dim3(GD, GD), dim3(GD), 0, stream>>>(density_grid, rec, cnt);
        pass_a<<<dim3(NRAYS / 2), dim3(NSAMP), 0, stream>>>(ray_pts, rec, outp, list, cnt, segcap);
        pass_b<<<dim3(256), dim3(256), 0, stream>>>(ray_pts, viewdirs, k0,
                                                    w0, b0, w1, b1, w2, b2,
                                                    list, cnt, segcap, outp);
    } else {
        dvgo_fallback<<<dim3(NRAYS), dim3(NSAMP), 0, stream>>>(ray_pts, density_grid, outp);
    }
}